// Round 8
// baseline (335.425 us; speedup 1.0000x reference)
//
#include <hip/hip_runtime.h>

#define B_  4
#define S_  2048
#define D_  1024
#define H_  16
#define HD_ 64
#define BS_ (B_*S_)   // 8192

typedef _Float16 f16;
typedef _Float16 f16_8 __attribute__((ext_vector_type(8)));
typedef _Float16 f16_4 __attribute__((ext_vector_type(4)));
typedef float    f32_4 __attribute__((ext_vector_type(4)));
typedef unsigned int u32;

#define MFMA32(a,b,c) __builtin_amdgcn_mfma_f32_16x16x32_f16(a, b, c, 0, 0, 0)
#define MFMA16(a,b,c) __builtin_amdgcn_mfma_f32_16x16x16f16(a, b, c, 0, 0, 0)
#define NEG_INF (-__builtin_inff())

// async global->LDS, 16B per lane. chunk_base in lane units (16B each).
__device__ inline void gl_lds16(const f16* g, f16* lds_base, int chunk_base) {
    __builtin_amdgcn_global_load_lds(
        (const __attribute__((address_space(1))) u32*)g,
        (__attribute__((address_space(3))) u32*)(lds_base + (size_t)chunk_base * 8),
        16, 0, 0);
}

// ---------------------------------------------------------------------------
// prep: blocks [0,4096) convert X fp32->f16; blocks [4096,4864) transpose
// W_attn fp32 [1024][3072] -> Wta f16 [3072][1024].
// ---------------------------------------------------------------------------
__global__ __launch_bounds__(256) void prep(
    const float* __restrict__ X,  f16* __restrict__ Xh,
    const float* __restrict__ Wa, f16* __restrict__ Wta)
{
    __shared__ f16 T[64][72];
    const int t = threadIdx.x;
    const int bid = blockIdx.x;
    if (bid < 4096) {
        const size_t i = ((size_t)bid * 256 + t) * 8;
        float4 a = *(const float4*)&X[i];
        float4 b = *(const float4*)&X[i + 4];
        f16 h[8] = {(f16)a.x,(f16)a.y,(f16)a.z,(f16)a.w,
                    (f16)b.x,(f16)b.y,(f16)b.z,(f16)b.w};
        *(uint4*)&Xh[i] = *(const uint4*)h;
        return;
    }
    const int idx = bid - 4096;
    const int n0 = (idx % 48) * 64, k0 = (idx / 48) * 64;
    const int nl4 = (t & 15) * 4;
    #pragma unroll
    for (int r = 0; r < 4; r++) {
        const int kl = (t >> 4) + r * 16;
        float4 v = *(const float4*)&Wa[(size_t)(k0 + kl) * 3072 + n0 + nl4];
        T[nl4 + 0][kl] = (f16)v.x;
        T[nl4 + 1][kl] = (f16)v.y;
        T[nl4 + 2][kl] = (f16)v.z;
        T[nl4 + 3][kl] = (f16)v.w;
    }
    __syncthreads();
    const int nr = t >> 2, kc = (t & 3) * 16;
    *(uint4*)&Wta[(size_t)(n0 + nr) * 1024 + k0 + kc]     = *(uint4*)&T[nr][kc];
    *(uint4*)&Wta[(size_t)(n0 + nr) * 1024 + k0 + kc + 8] = *(uint4*)&T[nr][kc + 8];
}

// ---------------------------------------------------------------------------
// Transpose + convert: W [1024][ncols] fp32 -> Wt [ncols][1024] f16
// (runs after attn: Wtp aliases the dead Q buffer)
// ---------------------------------------------------------------------------
__global__ __launch_bounds__(256) void trans_w(
    const float* __restrict__ W, f16* __restrict__ Wt, int ncols)
{
    __shared__ f16 T[64][72];
    const int t = threadIdx.x;
    const int n0 = blockIdx.x * 64, k0 = blockIdx.y * 64;
    const int nl4 = (t & 15) * 4;
    #pragma unroll
    for (int r = 0; r < 4; r++) {
        const int kl = (t >> 4) + r * 16;
        float4 v = *(const float4*)&W[(size_t)(k0 + kl) * ncols + n0 + nl4];
        T[nl4 + 0][kl] = (f16)v.x;
        T[nl4 + 1][kl] = (f16)v.y;
        T[nl4 + 2][kl] = (f16)v.z;
        T[nl4 + 3][kl] = (f16)v.w;
    }
    __syncthreads();
    const int nr = t >> 2, kc = (t & 3) * 16;
    *(uint4*)&Wt[(size_t)(n0 + nr) * 1024 + k0 + kc]     = *(uint4*)&T[nr][kc];
    *(uint4*)&Wt[(size_t)(n0 + nr) * 1024 + k0 + kc + 8] = *(uint4*)&T[nr][kc + 8];
}

// ---------------------------------------------------------------------------
// GEMM1: qkv = x @ W_attn + b_attn.  f16 operands, full async staging,
// 128x128 tile, BK=64 as 2x[128][32] chunks.
// ---------------------------------------------------------------------------
__global__ __launch_bounds__(256) void qkv_gemm(
    const f16*   __restrict__ Xh,    // [8192,1024] f16
    const f16*   __restrict__ Wta,   // [3072,1024] f16 (pre-transposed)
    const float* __restrict__ bias,  // [3072]
    f16* __restrict__ Qb, f16* __restrict__ Kb, f16* __restrict__ Vt)
{
    __shared__ f16 lds[17408];          // 34.8 KB (epilogue Ct reuse)
    f16* Af[2] = {lds,        lds + 4096};
    f16* Bf[2] = {lds + 8192, lds + 12288};
    f16* Ct    = lds;                   // [128][136]

    const int t    = threadIdx.x;
    const int lane = t & 63;
    const int w    = t >> 6;
    const int quad = lane >> 4, l15 = lane & 15;
    const int wr = w >> 1, wc = w & 1;
    const int n0 = blockIdx.x * 128;
    const int m0 = blockIdx.y * 128;
    const int wbase = t & 192;          // wave-uniform

    f32_4 acc[4][4] = {};

    for (int k0 = 0; k0 < 1024; k0 += 64) {
        #pragma unroll
        for (int kc = 0; kc < 2; kc++)
            #pragma unroll
            for (int c = 0; c < 2; c++) {
                int i = c*256 + t;
                const int row = i >> 2, col = (i & 3) * 8;
                gl_lds16(Xh  + (size_t)(m0 + row)*1024 + k0 + kc*32 + col,
                         Af[kc], c*256 + wbase);
                gl_lds16(Wta + (size_t)(n0 + row)*1024 + k0 + kc*32 + col,
                         Bf[kc], c*256 + wbase);
            }
        __syncthreads();

        #pragma unroll
        for (int kc = 0; kc < 2; kc++) {
            f16_8 af[4], bf[4];
            #pragma unroll
            for (int mi = 0; mi < 4; mi++)
                af[mi] = *(const f16_8*)&Af[kc][(wr*64 + mi*16 + l15)*32 + quad*8];
            #pragma unroll
            for (int ni = 0; ni < 4; ni++)
                bf[ni] = *(const f16_8*)&Bf[kc][(wc*64 + ni*16 + l15)*32 + quad*8];
            #pragma unroll
            for (int mi = 0; mi < 4; mi++)
                #pragma unroll
                for (int ni = 0; ni < 4; ni++)
                    acc[mi][ni] = MFMA32(af[mi], bf[ni], acc[mi][ni]);
        }
        __syncthreads();
    }

    const int which = n0 >> 10;      // 0=Q 1=K 2=V (block-uniform)
    float bcol[4];
    #pragma unroll
    for (int ni = 0; ni < 4; ni++)
        bcol[ni] = bias[n0 + wc*64 + ni*16 + l15];

    if (which < 2) {
        f16* dst = (which == 0) ? Qb : Kb;
        const float sc = (which == 0) ? 0.125f * 1.44269504f : 1.0f;
        #pragma unroll
        for (int mi = 0; mi < 4; mi++)
        #pragma unroll
        for (int ni = 0; ni < 4; ni++)
        #pragma unroll
        for (int r = 0; r < 4; r++) {
            int m = m0 + wr*64 + mi*16 + quad*4 + r;
            int n = (n0 & 1023) + wc*64 + ni*16 + l15;
            int h = n >> 6, hd = n & 63;
            int b = m >> 11, s = m & 2047;
            dst[((size_t)(b*16 + h)*2048 + s)*64 + hd] =
                (f16)((acc[mi][ni][r] + bcol[ni]) * sc);
        }
    } else {
        #pragma unroll
        for (int mi = 0; mi < 4; mi++)
        #pragma unroll
        for (int ni = 0; ni < 4; ni++)
        #pragma unroll
        for (int r = 0; r < 4; r++) {
            int nl = wc*64 + ni*16 + l15;
            int ml = wr*64 + mi*16 + quad*4 + r;
            Ct[nl*136 + ml] = (f16)(acc[mi][ni][r] + bcol[ni]);
        }
        __syncthreads();
        const int row = t >> 1, sc4 = (t & 1) * 64;
        const int n = (n0 & 1023) + row;
        const int h = n >> 6, hd = n & 63;
        const int b = m0 >> 11, s0 = (m0 & 2047) + sc4;
        f16* dst = Vt + ((size_t)(b*16 + h)*64 + hd)*2048 + s0;
        #pragma unroll
        for (int j = 0; j < 8; j++)
            *(uint4*)&dst[j*8] = *(uint4*)&Ct[row*136 + sc4 + j*8];
    }
}

// ---------------------------------------------------------------------------
// Flash causal attention: ONE 128-row q-strip per block, grid 16x64 = 1024
// blocks (4/CU resident). LPT order: qb = 15 - blockIdx.x so the longest
// strips (32 key-tiles) dispatch first and short strips backfill the tail.
// Fixed-max exp2 softmax, P^T in registers (S^T = K Q^T), l via MFMA vs ones.
// ---------------------------------------------------------------------------
__global__ __launch_bounds__(256) void attn(
    const f16* __restrict__ Qb,
    const f16* __restrict__ Kb,
    const f16* __restrict__ Vt,     // [bh][hd][s]
    f16* __restrict__ Y)            // [8192,1024]
{
    __shared__ f16 Ks[64*72];       // [key][hd]
    __shared__ f16 Vs[64*72];       // [hd][key]

    const int t    = threadIdx.x;
    const int w    = t >> 6;
    const int lane = t & 63;
    const int quad = lane >> 4, l15 = lane & 15;
    const int bh   = blockIdx.y;
    const int b    = bh >> 4, h = bh & 15;

    const f16* qh = Qb + (size_t)bh * S_ * 64;
    const f16* kh = Kb + (size_t)bh * S_ * 64;
    const f16* vt = Vt + (size_t)bh * 64 * S_;

    const int sk = t >> 2, sc = (t & 3) * 8;
    const f16_4 ones = {(f16)1,(f16)1,(f16)1,(f16)1};

    const int qb = 15 - (int)blockIdx.x;     // LPT: longest strip first
    const int qw = qb*128 + w*32;

    f16_8 qa[2][2];
    #pragma unroll
    for (int rt = 0; rt < 2; rt++)
        #pragma unroll
        for (int c = 0; c < 2; c++)
            qa[rt][c] = *(const f16_8*)&qh[(size_t)(qw + rt*16 + l15)*64 + c*32 + quad*8];

    f32_4 o[2][4] = {};
    f32_4 lacc[2] = {};
    const int ntiles = 2*qb + 2;

    for (int kt = 0; kt < ntiles; kt++) {
        const int kbase = kt * 64;
        *(uint4*)&Ks[sk*72 + sc]      = *(const uint4*)&kh[(size_t)(kbase + sk)*64 + sc];
        *(uint4*)&Ks[sk*72 + sc + 32] = *(const uint4*)&kh[(size_t)(kbase + sk)*64 + sc + 32];
        *(uint4*)&Vs[sk*72 + sc]      = *(const uint4*)&vt[(size_t)sk*2048 + kbase + sc];
        *(uint4*)&Vs[sk*72 + sc + 32] = *(const uint4*)&vt[(size_t)sk*2048 + kbase + sc + 32];
        __syncthreads();

        if (kbase <= qw + 31) {      // wave-uniform
            // ---- S^T = K Q^T : rows=key(quad*4+r), cols=qrow(l15) ----
            f16_8 kb[4][2];
            #pragma unroll
            for (int sub = 0; sub < 4; sub++)
                #pragma unroll
                for (int c = 0; c < 2; c++)
                    kb[sub][c] = *(const f16_8*)&Ks[(sub*16 + l15)*72 + c*32 + quad*8];
            f32_4 st[2][4];
            #pragma unroll
            for (int rt = 0; rt < 2; rt++)
                #pragma unroll
                for (int sub = 0; sub < 4; sub++) {
                    f32_4 a = {};
                    a = MFMA32(kb[sub][0], qa[rt][0], a);
                    a = MFMA32(kb[sub][1], qa[rt][1], a);
                    st[rt][sub] = a;
                }

            // ---- P^T = exp2(S^T), packed as 16x16x16 A-fragments ----
            const bool masked = (kbase + 63 > qw);
            f16_4 pt[2][4];
            #pragma unroll
            for (int rt = 0; rt < 2; rt++)
            #pragma unroll
            for (int sub = 0; sub < 4; sub++) {
                const int qrow = qw + rt*16 + l15;
                f16_4 p;
                #pragma unroll
                for (int r = 0; r < 4; r++) {
                    float x = st[rt][sub][r];
                    if (masked) {
                        int key = kbase + sub*16 + quad*4 + r;
                        x = (key <= qrow) ? x : NEG_INF;
                    }
                    p[r] = (f16)__builtin_amdgcn_exp2f(x);
                }
                pt[rt][sub] = p;
            }

            // ---- O += P V ; l += P . 1 ----
            #pragma unroll
            for (int sub = 0; sub < 4; sub++) {
                f16_4 vb[4];
                #pragma unroll
                for (int tt = 0; tt < 4; tt++)
                    vb[tt] = *(const f16_4*)&Vs[(tt*16 + l15)*72 + sub*16 + quad*4];
                #pragma unroll
                for (int rt = 0; rt < 2; rt++) {
                    lacc[rt] = MFMA16(pt[rt][sub], ones, lacc[rt]);
                    #pragma unroll
                    for (int tt = 0; tt < 4; tt++)
                        o[rt][tt] = MFMA16(pt[rt][sub], vb[tt], o[rt][tt]);
                }
            }
        }
        __syncthreads();
    }

    // epilogue: normalize, write Y
    #pragma unroll
    for (int rt = 0; rt < 2; rt++)
    #pragma unroll
    for (int r = 0; r < 4; r++) {
        float inv = 1.0f / lacc[rt][r];
        int srow = qw + rt*16 + quad*4 + r;
        #pragma unroll
        for (int tt = 0; tt < 4; tt++)
            Y[(size_t)(b*S_ + srow)*1024 + h*64 + tt*16 + l15] =
                (f16)(o[rt][tt][r] * inv);
    }
}

// ---------------------------------------------------------------------------
// GEMM2: out = y @ W_proj + b_proj.  Full async, BK=64 double-chunk.
// ---------------------------------------------------------------------------
__global__ __launch_bounds__(256) void proj_gemm(
    const f16* __restrict__ Yb,     // [8192,1024]
    const f16* __restrict__ Wtp,    // [1024,1024] (pre-transposed)
    const float* __restrict__ bias, // [1024]
    float* __restrict__ Out)        // [8192,1024] fp32
{
    __shared__ f16 lds2[16384];     // 32 KB
    f16* Af[2] = {lds2,        lds2 + 4096};
    f16* Bf[2] = {lds2 + 8192, lds2 + 12288};

    const int t    = threadIdx.x;
    const int lane = t & 63;
    const int w    = t >> 6;
    const int quad = lane >> 4, l15 = lane & 15;
    const int wr = w >> 1, wc = w & 1;
    const int n0 = blockIdx.x * 128;
    const int m0 = blockIdx.y * 128;
    const int wbase = t & 192;

    f32_4 acc[4][4] = {};

    for (int k0 = 0; k0 < 1024; k0 += 64) {
        #pragma unroll
        for (int kc = 0; kc < 2; kc++)
            #pragma unroll
            for (int c = 0; c < 2; c++) {
                int i = c*256 + t;
                const int row = i >> 2, col = (i & 3) * 8;
                gl_lds16(Yb  + (size_t)(m0 + row)*1024 + k0 + kc*32 + col,
                         Af[kc], c*256 + wbase);
                gl_lds16(Wtp + (size_t)(n0 + row)*1024 + k0 + kc*32 + col,
                         Bf[kc], c*256 + wbase);
            }
        __syncthreads();
        #pragma unroll
        for (int kc = 0; kc < 2; kc++) {
            f16_8 af[4], bf[4];
            #pragma unroll
            for (int mi = 0; mi < 4; mi++)
                af[mi] = *(const f16_8*)&Af[kc][(wr*64 + mi*16 + l15)*32 + quad*8];
            #pragma unroll
            for (int ni = 0; ni < 4; ni++)
                bf[ni] = *(const f16_8*)&Bf[kc][(wc*64 + ni*16 + l15)*32 + quad*8];
            #pragma unroll
            for (int mi = 0; mi < 4; mi++)
                #pragma unroll
                for (int ni = 0; ni < 4; ni++)
                    acc[mi][ni] = MFMA32(af[mi], bf[ni], acc[mi][ni]);
        }
        __syncthreads();
    }

    #pragma unroll
    for (int mi = 0; mi < 4; mi++)
    #pragma unroll
    for (int ni = 0; ni < 4; ni++)
    #pragma unroll
    for (int r = 0; r < 4; r++) {
        int m = m0 + wr*64 + mi*16 + quad*4 + r;
        int n = n0 + wc*64 + ni*16 + l15;
        Out[(size_t)m*1024 + n] = acc[mi][ni][r] + bias[n];
    }
}

// ---------------------------------------------------------------------------
extern "C" void kernel_launch(void* const* d_in, const int* in_sizes, int n_in,
                              void* d_out, int out_size, void* d_ws, size_t ws_size,
                              hipStream_t stream) {
    const float* x      = (const float*)d_in[0];
    const float* W_attn = (const float*)d_in[1];
    const float* b_attn = (const float*)d_in[2];
    const float* W_proj = (const float*)d_in[3];
    const float* b_proj = (const float*)d_in[4];
    float* out = (float*)d_out;

    const size_t per = (size_t)B_ * H_ * S_ * HD_;   // 8,388,608 elems
    f16* Yb  = (f16*)d_ws;        // [0, per)      attn output
    f16* Wta = Yb;                //   alias: W_attn^T f16 (dead before Yb written)
    f16* Qb  = Yb + per;          // [per, 2per)
    f16* Kb  = Qb + per;          // [2per, 3per)
    f16* Vt  = Kb + per;          // [3per, 4per)  total 67.1 MB
    f16* Wtp = Qb;                //   alias: W_proj^T f16 (written after attn)
    f16* Xh  = (f16*)d_out;       //   scratch: d_out dead until proj_gemm

    prep     <<<4096 + 768, 256, 0, stream>>>(x, Xh, W_attn, Wta);
    qkv_gemm <<<dim3(24, 64), 256, 0, stream>>>(Xh, Wta, b_attn, Qb, Kb, Vt);
    attn     <<<dim3(16, 64), 256, 0, stream>>>(Qb, Kb, Vt, Yb);
    trans_w  <<<dim3(16, 16), 256, 0, stream>>>(W_proj, Wtp, D_);
    proj_gemm<<<dim3(8, 64),  256, 0, stream>>>(Yb, Wtp, b_proj, out);
}

// Round 9
// 308.774 us; speedup vs baseline: 1.0863x; 1.0863x over previous
//
#include <hip/hip_runtime.h>

#define B_  4
#define S_  2048
#define D_  1024
#define H_  16
#define HD_ 64
#define BS_ (B_*S_)   // 8192

typedef _Float16 f16;
typedef _Float16 f16_8 __attribute__((ext_vector_type(8)));
typedef _Float16 f16_4 __attribute__((ext_vector_type(4)));
typedef float    f32_4 __attribute__((ext_vector_type(4)));
typedef unsigned int u32;

#define MFMA32(a,b,c) __builtin_amdgcn_mfma_f32_16x16x32_f16(a, b, c, 0, 0, 0)
#define MFMA16(a,b,c) __builtin_amdgcn_mfma_f32_16x16x16f16(a, b, c, 0, 0, 0)
#define NEG_INF (-__builtin_inff())

// async global->LDS, 16B per lane. chunk_base in lane units (16B each).
__device__ inline void gl_lds16(const f16* g, f16* lds_base, int chunk_base) {
    __builtin_amdgcn_global_load_lds(
        (const __attribute__((address_space(1))) u32*)g,
        (__attribute__((address_space(3))) u32*)(lds_base + (size_t)chunk_base * 8),
        16, 0, 0);
}

// ---------------------------------------------------------------------------
// prep: blocks [0,4096) convert X fp32->f16; blocks [4096,4864) transpose
// W_attn fp32 [1024][3072] -> Wta f16 [3072][1024].
// ---------------------------------------------------------------------------
__global__ __launch_bounds__(256) void prep(
    const float* __restrict__ X,  f16* __restrict__ Xh,
    const float* __restrict__ Wa, f16* __restrict__ Wta)
{
    __shared__ f16 T[64][72];
    const int t = threadIdx.x;
    const int bid = blockIdx.x;
    if (bid < 4096) {
        const size_t i = ((size_t)bid * 256 + t) * 8;
        float4 a = *(const float4*)&X[i];
        float4 b = *(const float4*)&X[i + 4];
        f16 h[8] = {(f16)a.x,(f16)a.y,(f16)a.z,(f16)a.w,
                    (f16)b.x,(f16)b.y,(f16)b.z,(f16)b.w};
        *(uint4*)&Xh[i] = *(const uint4*)h;
        return;
    }
    const int idx = bid - 4096;
    const int n0 = (idx % 48) * 64, k0 = (idx / 48) * 64;
    const int nl4 = (t & 15) * 4;
    #pragma unroll
    for (int r = 0; r < 4; r++) {
        const int kl = (t >> 4) + r * 16;
        float4 v = *(const float4*)&Wa[(size_t)(k0 + kl) * 3072 + n0 + nl4];
        T[nl4 + 0][kl] = (f16)v.x;
        T[nl4 + 1][kl] = (f16)v.y;
        T[nl4 + 2][kl] = (f16)v.z;
        T[nl4 + 3][kl] = (f16)v.w;
    }
    __syncthreads();
    const int nr = t >> 2, kc = (t & 3) * 16;
    *(uint4*)&Wta[(size_t)(n0 + nr) * 1024 + k0 + kc]     = *(uint4*)&T[nr][kc];
    *(uint4*)&Wta[(size_t)(n0 + nr) * 1024 + k0 + kc + 8] = *(uint4*)&T[nr][kc + 8];
}

// ---------------------------------------------------------------------------
// Transpose + convert: W [1024][ncols] fp32 -> Wt [ncols][1024] f16
// (runs after attn: Wtp aliases the dead Q buffer)
// ---------------------------------------------------------------------------
__global__ __launch_bounds__(256) void trans_w(
    const float* __restrict__ W, f16* __restrict__ Wt, int ncols)
{
    __shared__ f16 T[64][72];
    const int t = threadIdx.x;
    const int n0 = blockIdx.x * 64, k0 = blockIdx.y * 64;
    const int nl4 = (t & 15) * 4;
    #pragma unroll
    for (int r = 0; r < 4; r++) {
        const int kl = (t >> 4) + r * 16;
        float4 v = *(const float4*)&W[(size_t)(k0 + kl) * ncols + n0 + nl4];
        T[nl4 + 0][kl] = (f16)v.x;
        T[nl4 + 1][kl] = (f16)v.y;
        T[nl4 + 2][kl] = (f16)v.z;
        T[nl4 + 3][kl] = (f16)v.w;
    }
    __syncthreads();
    const int nr = t >> 2, kc = (t & 3) * 16;
    *(uint4*)&Wt[(size_t)(n0 + nr) * 1024 + k0 + kc]     = *(uint4*)&T[nr][kc];
    *(uint4*)&Wt[(size_t)(n0 + nr) * 1024 + k0 + kc + 8] = *(uint4*)&T[nr][kc + 8];
}

// ---------------------------------------------------------------------------
// GEMM1: qkv = x @ W_attn + b_attn.  f16 operands, full async staging,
// 128x128 tile, BK=64 as 2x[128][32] chunks.
// ---------------------------------------------------------------------------
__global__ __launch_bounds__(256) void qkv_gemm(
    const f16*   __restrict__ Xh,    // [8192,1024] f16
    const f16*   __restrict__ Wta,   // [3072,1024] f16 (pre-transposed)
    const float* __restrict__ bias,  // [3072]
    f16* __restrict__ Qb, f16* __restrict__ Kb, f16* __restrict__ Vt)
{
    __shared__ f16 lds[17408];          // 34.8 KB (epilogue Ct reuse)
    f16* Af[2] = {lds,        lds + 4096};
    f16* Bf[2] = {lds + 8192, lds + 12288};
    f16* Ct    = lds;                   // [128][136]

    const int t    = threadIdx.x;
    const int lane = t & 63;
    const int w    = t >> 6;
    const int quad = lane >> 4, l15 = lane & 15;
    const int wr = w >> 1, wc = w & 1;
    const int n0 = blockIdx.x * 128;
    const int m0 = blockIdx.y * 128;
    const int wbase = t & 192;          // wave-uniform

    f32_4 acc[4][4] = {};

    for (int k0 = 0; k0 < 1024; k0 += 64) {
        #pragma unroll
        for (int kc = 0; kc < 2; kc++)
            #pragma unroll
            for (int c = 0; c < 2; c++) {
                int i = c*256 + t;
                const int row = i >> 2, col = (i & 3) * 8;
                gl_lds16(Xh  + (size_t)(m0 + row)*1024 + k0 + kc*32 + col,
                         Af[kc], c*256 + wbase);
                gl_lds16(Wta + (size_t)(n0 + row)*1024 + k0 + kc*32 + col,
                         Bf[kc], c*256 + wbase);
            }
        __syncthreads();

        #pragma unroll
        for (int kc = 0; kc < 2; kc++) {
            f16_8 af[4], bf[4];
            #pragma unroll
            for (int mi = 0; mi < 4; mi++)
                af[mi] = *(const f16_8*)&Af[kc][(wr*64 + mi*16 + l15)*32 + quad*8];
            #pragma unroll
            for (int ni = 0; ni < 4; ni++)
                bf[ni] = *(const f16_8*)&Bf[kc][(wc*64 + ni*16 + l15)*32 + quad*8];
            #pragma unroll
            for (int mi = 0; mi < 4; mi++)
                #pragma unroll
                for (int ni = 0; ni < 4; ni++)
                    acc[mi][ni] = MFMA32(af[mi], bf[ni], acc[mi][ni]);
        }
        __syncthreads();
    }

    const int which = n0 >> 10;      // 0=Q 1=K 2=V (block-uniform)
    float bcol[4];
    #pragma unroll
    for (int ni = 0; ni < 4; ni++)
        bcol[ni] = bias[n0 + wc*64 + ni*16 + l15];

    if (which < 2) {
        f16* dst = (which == 0) ? Qb : Kb;
        const float sc = (which == 0) ? 0.125f * 1.44269504f : 1.0f;
        #pragma unroll
        for (int mi = 0; mi < 4; mi++)
        #pragma unroll
        for (int ni = 0; ni < 4; ni++)
        #pragma unroll
        for (int r = 0; r < 4; r++) {
            int m = m0 + wr*64 + mi*16 + quad*4 + r;
            int n = (n0 & 1023) + wc*64 + ni*16 + l15;
            int h = n >> 6, hd = n & 63;
            int b = m >> 11, s = m & 2047;
            dst[((size_t)(b*16 + h)*2048 + s)*64 + hd] =
                (f16)((acc[mi][ni][r] + bcol[ni]) * sc);
        }
    } else {
        #pragma unroll
        for (int mi = 0; mi < 4; mi++)
        #pragma unroll
        for (int ni = 0; ni < 4; ni++)
        #pragma unroll
        for (int r = 0; r < 4; r++) {
            int nl = wc*64 + ni*16 + l15;
            int ml = wr*64 + mi*16 + quad*4 + r;
            Ct[nl*136 + ml] = (f16)(acc[mi][ni][r] + bcol[ni]);
        }
        __syncthreads();
        const int row = t >> 1, sc4 = (t & 1) * 64;
        const int n = (n0 & 1023) + row;
        const int h = n >> 6, hd = n & 63;
        const int b = m0 >> 11, s0 = (m0 & 2047) + sc4;
        f16* dst = Vt + ((size_t)(b*16 + h)*64 + hd)*2048 + s0;
        #pragma unroll
        for (int j = 0; j < 8; j++)
            *(uint4*)&dst[j*8] = *(uint4*)&Ct[row*136 + sc4 + j*8];
    }
}

// ---------------------------------------------------------------------------
// Flash causal attention: 2-wave blocks (128 thr), 64-row strips, pair
// {j, 31-j} processed as two sequential passes -> UNIFORM 33 tiles/block,
// grid 16x64 = 1024 blocks. Masked diagonal tile split out of the hot loop.
// Fixed-max exp2 softmax, P^T in registers (S^T = K Q^T), l via one MFMA on
// the sub-summed P fragment.
// ---------------------------------------------------------------------------
__global__ __launch_bounds__(128) void attn(
    const f16* __restrict__ Qb,
    const f16* __restrict__ Kb,
    const f16* __restrict__ Vt,     // [bh][hd][s]
    f16* __restrict__ Y)            // [8192,1024]
{
    __shared__ f16 Ks[64*72];       // [key][hd]
    __shared__ f16 Vs[64*72];       // [hd][key]

    const int t    = threadIdx.x;
    const int w    = t >> 6;        // 0..1
    const int lane = t & 63;
    const int quad = lane >> 4, l15 = lane & 15;
    const int bh   = blockIdx.y;
    const int b    = bh >> 4, h = bh & 15;

    const f16* qh = Qb + (size_t)bh * S_ * 64;
    const f16* kh = Kb + (size_t)bh * S_ * 64;
    const f16* vt = Vt + (size_t)bh * 64 * S_;

    const int srow  = t >> 1;        // 0..63 staging row (key for Ks, hd for Vs)
    const int shalf = (t & 1) * 32;  // 0 / 32
    const f16_4 ones = {(f16)1,(f16)1,(f16)1,(f16)1};

    #pragma unroll 1
    for (int sp = 0; sp < 2; sp++) {
        const int strip  = sp ? 31 - (int)blockIdx.x : (int)blockIdx.x;
        const int qw     = strip*64 + w*32;
        const int ntiles = strip + 1;

        f16_8 qa[2][2];
        #pragma unroll
        for (int rt = 0; rt < 2; rt++)
            #pragma unroll
            for (int c = 0; c < 2; c++)
                qa[rt][c] = *(const f16_8*)&qh[(size_t)(qw + rt*16 + l15)*64 + c*32 + quad*8];

        f32_4 o[2][4] = {};
        f32_4 lacc[2] = {};

        auto stage = [&](int kbase) {
            #pragma unroll
            for (int j = 0; j < 4; j++) {
                *(uint4*)&Ks[srow*72 + shalf + j*8] =
                    *(const uint4*)&kh[(size_t)(kbase + srow)*64 + shalf + j*8];
                *(uint4*)&Vs[srow*72 + shalf + j*8] =
                    *(const uint4*)&vt[(size_t)srow*2048 + kbase + shalf + j*8];
            }
        };

        auto tilec = [&](int kbase, bool masked) {
            // ---- S^T = K Q^T : rows=key(quad*4+r), cols=qrow(l15) ----
            f16_8 kbf[4][2];
            #pragma unroll
            for (int sub = 0; sub < 4; sub++)
                #pragma unroll
                for (int c = 0; c < 2; c++)
                    kbf[sub][c] = *(const f16_8*)&Ks[(sub*16 + l15)*72 + c*32 + quad*8];
            f32_4 st[2][4];
            #pragma unroll
            for (int rt = 0; rt < 2; rt++)
                #pragma unroll
                for (int sub = 0; sub < 4; sub++) {
                    f32_4 a = {};
                    a = MFMA32(kbf[sub][0], qa[rt][0], a);
                    a = MFMA32(kbf[sub][1], qa[rt][1], a);
                    st[rt][sub] = a;
                }

            // ---- P^T = exp2(S^T), packed as 16x16x16 A-fragments ----
            f16_4 pt[2][4];
            #pragma unroll
            for (int rt = 0; rt < 2; rt++)
            #pragma unroll
            for (int sub = 0; sub < 4; sub++) {
                const int qrow = qw + rt*16 + l15;
                f16_4 p;
                #pragma unroll
                for (int r = 0; r < 4; r++) {
                    float x = st[rt][sub][r];
                    if (masked) {
                        int key = kbase + sub*16 + quad*4 + r;
                        x = (key <= qrow) ? x : NEG_INF;
                    }
                    p[r] = (f16)__builtin_amdgcn_exp2f(x);
                }
                pt[rt][sub] = p;
            }

            // ---- l += (sum_sub P) . 1  (one MFMA per rt) ----
            #pragma unroll
            for (int rt = 0; rt < 2; rt++) {
                f16_4 ps = (pt[rt][0] + pt[rt][1]) + (pt[rt][2] + pt[rt][3]);
                lacc[rt] = MFMA16(ps, ones, lacc[rt]);
            }

            // ---- O += P V ----
            #pragma unroll
            for (int sub = 0; sub < 4; sub++) {
                f16_4 vb[4];
                #pragma unroll
                for (int tt = 0; tt < 4; tt++)
                    vb[tt] = *(const f16_4*)&Vs[(tt*16 + l15)*72 + sub*16 + quad*4];
                #pragma unroll
                for (int rt = 0; rt < 2; rt++)
                    #pragma unroll
                    for (int tt = 0; tt < 4; tt++)
                        o[rt][tt] = MFMA16(pt[rt][sub], vb[tt], o[rt][tt]);
            }
        };

        #pragma unroll 1
        for (int kt = 0; kt < ntiles - 1; kt++) {
            stage(kt*64);
            __syncthreads();
            tilec(kt*64, false);            // interior: branch-free, no mask
            __syncthreads();
        }
        stage((ntiles-1)*64);
        __syncthreads();
        tilec((ntiles-1)*64, true);         // diagonal tile: masked
        __syncthreads();

        // epilogue: normalize, write Y
        #pragma unroll
        for (int rt = 0; rt < 2; rt++)
        #pragma unroll
        for (int r = 0; r < 4; r++) {
            float inv = 1.0f / lacc[rt][r];
            int sr = qw + rt*16 + quad*4 + r;
            #pragma unroll
            for (int tt = 0; tt < 4; tt++)
                Y[(size_t)(b*S_ + sr)*1024 + h*64 + tt*16 + l15] =
                    (f16)(o[rt][tt][r] * inv);
        }
    }
}

// ---------------------------------------------------------------------------
// GEMM2: out = y @ W_proj + b_proj.  Full async, BK=64 double-chunk.
// ---------------------------------------------------------------------------
__global__ __launch_bounds__(256) void proj_gemm(
    const f16* __restrict__ Yb,     // [8192,1024]
    const f16* __restrict__ Wtp,    // [1024,1024] (pre-transposed)
    const float* __restrict__ bias, // [1024]
    float* __restrict__ Out)        // [8192,1024] fp32
{
    __shared__ f16 lds2[16384];     // 32 KB
    f16* Af[2] = {lds2,        lds2 + 4096};
    f16* Bf[2] = {lds2 + 8192, lds2 + 12288};

    const int t    = threadIdx.x;
    const int lane = t & 63;
    const int w    = t >> 6;
    const int quad = lane >> 4, l15 = lane & 15;
    const int wr = w >> 1, wc = w & 1;
    const int n0 = blockIdx.x * 128;
    const int m0 = blockIdx.y * 128;
    const int wbase = t & 192;

    f32_4 acc[4][4] = {};

    for (int k0 = 0; k0 < 1024; k0 += 64) {
        #pragma unroll
        for (int kc = 0; kc < 2; kc++)
            #pragma unroll
            for (int c = 0; c < 2; c++) {
                int i = c*256 + t;
                const int row = i >> 2, col = (i & 3) * 8;
                gl_lds16(Yb  + (size_t)(m0 + row)*1024 + k0 + kc*32 + col,
                         Af[kc], c*256 + wbase);
                gl_lds16(Wtp + (size_t)(n0 + row)*1024 + k0 + kc*32 + col,
                         Bf[kc], c*256 + wbase);
            }
        __syncthreads();
        #pragma unroll
        for (int kc = 0; kc < 2; kc++) {
            f16_8 af[4], bf[4];
            #pragma unroll
            for (int mi = 0; mi < 4; mi++)
                af[mi] = *(const f16_8*)&Af[kc][(wr*64 + mi*16 + l15)*32 + quad*8];
            #pragma unroll
            for (int ni = 0; ni < 4; ni++)
                bf[ni] = *(const f16_8*)&Bf[kc][(wc*64 + ni*16 + l15)*32 + quad*8];
            #pragma unroll
            for (int mi = 0; mi < 4; mi++)
                #pragma unroll
                for (int ni = 0; ni < 4; ni++)
                    acc[mi][ni] = MFMA32(af[mi], bf[ni], acc[mi][ni]);
        }
        __syncthreads();
    }

    #pragma unroll
    for (int mi = 0; mi < 4; mi++)
    #pragma unroll
    for (int ni = 0; ni < 4; ni++)
    #pragma unroll
    for (int r = 0; r < 4; r++) {
        int m = m0 + wr*64 + mi*16 + quad*4 + r;
        int n = n0 + wc*64 + ni*16 + l15;
        Out[(size_t)m*1024 + n] = acc[mi][ni][r] + bias[n];
    }
}

// ---------------------------------------------------------------------------
extern "C" void kernel_launch(void* const* d_in, const int* in_sizes, int n_in,
                              void* d_out, int out_size, void* d_ws, size_t ws_size,
                              hipStream_t stream) {
    const float* x      = (const float*)d_in[0];
    const float* W_attn = (const float*)d_in[1];
    const float* b_attn = (const float*)d_in[2];
    const float* W_proj = (const float*)d_in[3];
    const float* b_proj = (const float*)d_in[4];
    float* out = (float*)d_out;

    const size_t per = (size_t)B_ * H_ * S_ * HD_;   // 8,388,608 elems
    f16* Yb  = (f16*)d_ws;        // [0, per)      attn output
    f16* Wta = Yb;                //   alias: W_attn^T f16 (dead before Yb written)
    f16* Qb  = Yb + per;          // [per, 2per)
    f16* Kb  = Qb + per;          // [2per, 3per)
    f16* Vt  = Kb + per;          // [3per, 4per)  total 67.1 MB
    f16* Wtp = Qb;                //   alias: W_proj^T f16 (written after attn)
    f16* Xh  = (f16*)d_out;       //   scratch: d_out dead until proj_gemm

    prep     <<<4096 + 768, 256, 0, stream>>>(x, Xh, W_attn, Wta);
    qkv_gemm <<<dim3(24, 64), 256, 0, stream>>>(Xh, Wta, b_attn, Qb, Kb, Vt);
    attn     <<<dim3(16, 64), 128, 0, stream>>>(Qb, Kb, Vt, Yb);
    trans_w  <<<dim3(16, 16), 256, 0, stream>>>(W_proj, Wtp, D_);
    proj_gemm<<<dim3(8, 64),  256, 0, stream>>>(Yb, Wtp, b_proj, out);
}

// Round 10
// 270.768 us; speedup vs baseline: 1.2388x; 1.1404x over previous
//
#include <hip/hip_runtime.h>

#define B_  4
#define S_  2048
#define D_  1024
#define H_  16
#define HD_ 64
#define BS_ (B_*S_)   // 8192

typedef _Float16 f16;
typedef _Float16 f16_8 __attribute__((ext_vector_type(8)));
typedef _Float16 f16_4 __attribute__((ext_vector_type(4)));
typedef float    f32_4 __attribute__((ext_vector_type(4)));
typedef unsigned int u32;

#define MFMA32(a,b,c) __builtin_amdgcn_mfma_f32_16x16x32_f16(a, b, c, 0, 0, 0)
#define MFMA16(a,b,c) __builtin_amdgcn_mfma_f32_16x16x16f16(a, b, c, 0, 0, 0)
#define NEG_INF (-__builtin_inff())

// async global->LDS, 16B per lane. chunk_base in lane units (16B each).
__device__ inline void gl_lds16(const f16* g, f16* lds_base, int chunk_base) {
    __builtin_amdgcn_global_load_lds(
        (const __attribute__((address_space(1))) u32*)g,
        (__attribute__((address_space(3))) u32*)(lds_base + (size_t)chunk_base * 8),
        16, 0, 0);
}

// ---------------------------------------------------------------------------
// prep: blocks [0,4096) convert X fp32->f16; blocks [4096,4864) transpose
// W_attn fp32 [1024][3072] -> Wta f16 [3072][1024].
// ---------------------------------------------------------------------------
__global__ __launch_bounds__(256) void prep(
    const float* __restrict__ X,  f16* __restrict__ Xh,
    const float* __restrict__ Wa, f16* __restrict__ Wta)
{
    __shared__ f16 T[64][72];
    const int t = threadIdx.x;
    const int bid = blockIdx.x;
    if (bid < 4096) {
        const size_t i = ((size_t)bid * 256 + t) * 8;
        float4 a = *(const float4*)&X[i];
        float4 b = *(const float4*)&X[i + 4];
        f16 h[8] = {(f16)a.x,(f16)a.y,(f16)a.z,(f16)a.w,
                    (f16)b.x,(f16)b.y,(f16)b.z,(f16)b.w};
        *(uint4*)&Xh[i] = *(const uint4*)h;
        return;
    }
    const int idx = bid - 4096;
    const int n0 = (idx % 48) * 64, k0 = (idx / 48) * 64;
    const int nl4 = (t & 15) * 4;
    #pragma unroll
    for (int r = 0; r < 4; r++) {
        const int kl = (t >> 4) + r * 16;
        float4 v = *(const float4*)&Wa[(size_t)(k0 + kl) * 3072 + n0 + nl4];
        T[nl4 + 0][kl] = (f16)v.x;
        T[nl4 + 1][kl] = (f16)v.y;
        T[nl4 + 2][kl] = (f16)v.z;
        T[nl4 + 3][kl] = (f16)v.w;
    }
    __syncthreads();
    const int nr = t >> 2, kc = (t & 3) * 16;
    *(uint4*)&Wta[(size_t)(n0 + nr) * 1024 + k0 + kc]     = *(uint4*)&T[nr][kc];
    *(uint4*)&Wta[(size_t)(n0 + nr) * 1024 + k0 + kc + 8] = *(uint4*)&T[nr][kc + 8];
}

// ---------------------------------------------------------------------------
// Transpose + convert: W [1024][ncols] fp32 -> Wt [ncols][1024] f16
// (runs after attn: Wtp aliases the dead Q buffer)
// ---------------------------------------------------------------------------
__global__ __launch_bounds__(256) void trans_w(
    const float* __restrict__ W, f16* __restrict__ Wt, int ncols)
{
    __shared__ f16 T[64][72];
    const int t = threadIdx.x;
    const int n0 = blockIdx.x * 64, k0 = blockIdx.y * 64;
    const int nl4 = (t & 15) * 4;
    #pragma unroll
    for (int r = 0; r < 4; r++) {
        const int kl = (t >> 4) + r * 16;
        float4 v = *(const float4*)&W[(size_t)(k0 + kl) * ncols + n0 + nl4];
        T[nl4 + 0][kl] = (f16)v.x;
        T[nl4 + 1][kl] = (f16)v.y;
        T[nl4 + 2][kl] = (f16)v.z;
        T[nl4 + 3][kl] = (f16)v.w;
    }
    __syncthreads();
    const int nr = t >> 2, kc = (t & 3) * 16;
    *(uint4*)&Wt[(size_t)(n0 + nr) * 1024 + k0 + kc]     = *(uint4*)&T[nr][kc];
    *(uint4*)&Wt[(size_t)(n0 + nr) * 1024 + k0 + kc + 8] = *(uint4*)&T[nr][kc + 8];
}

// ---------------------------------------------------------------------------
// GEMM1: qkv = x @ W_attn + b_attn.  f16 operands, full async staging,
// 128x128 tile, BK=64 as 2x[128][32] chunks.
// ---------------------------------------------------------------------------
__global__ __launch_bounds__(256) void qkv_gemm(
    const f16*   __restrict__ Xh,    // [8192,1024] f16
    const f16*   __restrict__ Wta,   // [3072,1024] f16 (pre-transposed)
    const float* __restrict__ bias,  // [3072]
    f16* __restrict__ Qb, f16* __restrict__ Kb, f16* __restrict__ Vt)
{
    __shared__ f16 lds[17408];          // 34.8 KB (epilogue Ct reuse)
    f16* Af[2] = {lds,        lds + 4096};
    f16* Bf[2] = {lds + 8192, lds + 12288};
    f16* Ct    = lds;                   // [128][136]

    const int t    = threadIdx.x;
    const int lane = t & 63;
    const int w    = t >> 6;
    const int quad = lane >> 4, l15 = lane & 15;
    const int wr = w >> 1, wc = w & 1;
    const int n0 = blockIdx.x * 128;
    const int m0 = blockIdx.y * 128;
    const int wbase = t & 192;          // wave-uniform

    f32_4 acc[4][4] = {};

    for (int k0 = 0; k0 < 1024; k0 += 64) {
        #pragma unroll
        for (int kc = 0; kc < 2; kc++)
            #pragma unroll
            for (int c = 0; c < 2; c++) {
                int i = c*256 + t;
                const int row = i >> 2, col = (i & 3) * 8;
                gl_lds16(Xh  + (size_t)(m0 + row)*1024 + k0 + kc*32 + col,
                         Af[kc], c*256 + wbase);
                gl_lds16(Wta + (size_t)(n0 + row)*1024 + k0 + kc*32 + col,
                         Bf[kc], c*256 + wbase);
            }
        __syncthreads();

        #pragma unroll
        for (int kc = 0; kc < 2; kc++) {
            f16_8 af[4], bf[4];
            #pragma unroll
            for (int mi = 0; mi < 4; mi++)
                af[mi] = *(const f16_8*)&Af[kc][(wr*64 + mi*16 + l15)*32 + quad*8];
            #pragma unroll
            for (int ni = 0; ni < 4; ni++)
                bf[ni] = *(const f16_8*)&Bf[kc][(wc*64 + ni*16 + l15)*32 + quad*8];
            #pragma unroll
            for (int mi = 0; mi < 4; mi++)
                #pragma unroll
                for (int ni = 0; ni < 4; ni++)
                    acc[mi][ni] = MFMA32(af[mi], bf[ni], acc[mi][ni]);
        }
        __syncthreads();
    }

    const int which = n0 >> 10;      // 0=Q 1=K 2=V (block-uniform)
    float bcol[4];
    #pragma unroll
    for (int ni = 0; ni < 4; ni++)
        bcol[ni] = bias[n0 + wc*64 + ni*16 + l15];

    if (which < 2) {
        f16* dst = (which == 0) ? Qb : Kb;
        const float sc = (which == 0) ? 0.125f * 1.44269504f : 1.0f;
        #pragma unroll
        for (int mi = 0; mi < 4; mi++)
        #pragma unroll
        for (int ni = 0; ni < 4; ni++)
        #pragma unroll
        for (int r = 0; r < 4; r++) {
            int m = m0 + wr*64 + mi*16 + quad*4 + r;
            int n = (n0 & 1023) + wc*64 + ni*16 + l15;
            int h = n >> 6, hd = n & 63;
            int b = m >> 11, s = m & 2047;
            dst[((size_t)(b*16 + h)*2048 + s)*64 + hd] =
                (f16)((acc[mi][ni][r] + bcol[ni]) * sc);
        }
    } else {
        #pragma unroll
        for (int mi = 0; mi < 4; mi++)
        #pragma unroll
        for (int ni = 0; ni < 4; ni++)
        #pragma unroll
        for (int r = 0; r < 4; r++) {
            int nl = wc*64 + ni*16 + l15;
            int ml = wr*64 + mi*16 + quad*4 + r;
            Ct[nl*136 + ml] = (f16)(acc[mi][ni][r] + bcol[ni]);
        }
        __syncthreads();
        const int row = t >> 1, sc4 = (t & 1) * 64;
        const int n = (n0 & 1023) + row;
        const int h = n >> 6, hd = n & 63;
        const int b = m0 >> 11, s0 = (m0 & 2047) + sc4;
        f16* dst = Vt + ((size_t)(b*16 + h)*64 + hd)*2048 + s0;
        #pragma unroll
        for (int j = 0; j < 8; j++)
            *(uint4*)&dst[j*8] = *(uint4*)&Ct[row*136 + sc4 + j*8];
    }
}

// ---------------------------------------------------------------------------
// Flash causal attention (round-5 structure): 4-wave blocks, 128-row strips,
// pair {qb, 15-qb} as two sequential passes (34 tiles/block, uniform).
// Grid (bh=64, pair=8): all 8 pair-blocks of one bh share linear id%8 ->
// same XCD under round-robin dispatch -> L2 caches that bh's K/V.
// Fixed-max exp2 softmax, P^T in registers, l via pre-summed P MFMA.
// ---------------------------------------------------------------------------
__global__ __launch_bounds__(256) void attn(
    const f16* __restrict__ Qb,
    const f16* __restrict__ Kb,
    const f16* __restrict__ Vt,     // [bh][hd][s]
    f16* __restrict__ Y)            // [8192,1024]
{
    __shared__ f16 Ks[64*72];       // [key][hd]
    __shared__ f16 Vs[64*72];       // [hd][key]

    const int t    = threadIdx.x;
    const int w    = t >> 6;
    const int lane = t & 63;
    const int quad = lane >> 4, l15 = lane & 15;
    const int bh   = blockIdx.x;    // swizzle: bh fastest -> same XCD
    const int b    = bh >> 4, h = bh & 15;

    const f16* qh = Qb + (size_t)bh * S_ * 64;
    const f16* kh = Kb + (size_t)bh * S_ * 64;
    const f16* vt = Vt + (size_t)bh * 64 * S_;

    const int sk = t >> 2, sc = (t & 3) * 8;
    const f16_4 ones = {(f16)1,(f16)1,(f16)1,(f16)1};

    #pragma unroll 1
    for (int sp = 0; sp < 2; sp++) {
        const int qb = sp ? 15 - (int)blockIdx.y : (int)blockIdx.y;
        const int qw = qb*128 + w*32;

        f16_8 qa[2][2];
        #pragma unroll
        for (int rt = 0; rt < 2; rt++)
            #pragma unroll
            for (int c = 0; c < 2; c++)
                qa[rt][c] = *(const f16_8*)&qh[(size_t)(qw + rt*16 + l15)*64 + c*32 + quad*8];

        f32_4 o[2][4] = {};
        f32_4 lacc[2] = {};
        const int ntiles = 2*qb + 2;

        for (int kt = 0; kt < ntiles; kt++) {
            const int kbase = kt * 64;
            *(uint4*)&Ks[sk*72 + sc]      = *(const uint4*)&kh[(size_t)(kbase + sk)*64 + sc];
            *(uint4*)&Ks[sk*72 + sc + 32] = *(const uint4*)&kh[(size_t)(kbase + sk)*64 + sc + 32];
            *(uint4*)&Vs[sk*72 + sc]      = *(const uint4*)&vt[(size_t)sk*2048 + kbase + sc];
            *(uint4*)&Vs[sk*72 + sc + 32] = *(const uint4*)&vt[(size_t)sk*2048 + kbase + sc + 32];
            __syncthreads();

            if (kbase <= qw + 31) {      // wave-uniform
                // ---- S^T = K Q^T : rows=key(quad*4+r), cols=qrow(l15) ----
                f16_8 kb[4][2];
                #pragma unroll
                for (int sub = 0; sub < 4; sub++)
                    #pragma unroll
                    for (int c = 0; c < 2; c++)
                        kb[sub][c] = *(const f16_8*)&Ks[(sub*16 + l15)*72 + c*32 + quad*8];
                f32_4 st[2][4];
                #pragma unroll
                for (int rt = 0; rt < 2; rt++)
                    #pragma unroll
                    for (int sub = 0; sub < 4; sub++) {
                        f32_4 a = {};
                        a = MFMA32(kb[sub][0], qa[rt][0], a);
                        a = MFMA32(kb[sub][1], qa[rt][1], a);
                        st[rt][sub] = a;
                    }

                // ---- P^T = exp2(S^T), packed as 16x16x16 A-fragments ----
                const bool masked = (kbase + 63 > qw);
                f16_4 pt[2][4];
                #pragma unroll
                for (int rt = 0; rt < 2; rt++)
                #pragma unroll
                for (int sub = 0; sub < 4; sub++) {
                    const int qrow = qw + rt*16 + l15;
                    f16_4 p;
                    #pragma unroll
                    for (int r = 0; r < 4; r++) {
                        float x = st[rt][sub][r];
                        if (masked) {
                            int key = kbase + sub*16 + quad*4 + r;
                            x = (key <= qrow) ? x : NEG_INF;
                        }
                        p[r] = (f16)__builtin_amdgcn_exp2f(x);
                    }
                    pt[rt][sub] = p;
                }

                // ---- l += (sum_sub P) . 1  (one MFMA per rt) ----
                #pragma unroll
                for (int rt = 0; rt < 2; rt++) {
                    f16_4 ps = (pt[rt][0] + pt[rt][1]) + (pt[rt][2] + pt[rt][3]);
                    lacc[rt] = MFMA16(ps, ones, lacc[rt]);
                }

                // ---- O += P V ----
                #pragma unroll
                for (int sub = 0; sub < 4; sub++) {
                    f16_4 vb[4];
                    #pragma unroll
                    for (int tt = 0; tt < 4; tt++)
                        vb[tt] = *(const f16_4*)&Vs[(tt*16 + l15)*72 + sub*16 + quad*4];
                    #pragma unroll
                    for (int rt = 0; rt < 2; rt++)
                        #pragma unroll
                        for (int tt = 0; tt < 4; tt++)
                            o[rt][tt] = MFMA16(pt[rt][sub], vb[tt], o[rt][tt]);
                }
            }
            __syncthreads();
        }

        // epilogue: normalize, write Y
        #pragma unroll
        for (int rt = 0; rt < 2; rt++)
        #pragma unroll
        for (int r = 0; r < 4; r++) {
            float inv = 1.0f / lacc[rt][r];
            int srow = qw + rt*16 + quad*4 + r;
            #pragma unroll
            for (int tt = 0; tt < 4; tt++)
                Y[(size_t)(b*S_ + srow)*1024 + h*64 + tt*16 + l15] =
                    (f16)(o[rt][tt][r] * inv);
        }
    }
}

// ---------------------------------------------------------------------------
// GEMM2: out = y @ W_proj + b_proj.  Full async, BK=64 double-chunk.
// ---------------------------------------------------------------------------
__global__ __launch_bounds__(256) void proj_gemm(
    const f16* __restrict__ Yb,     // [8192,1024]
    const f16* __restrict__ Wtp,    // [1024,1024] (pre-transposed)
    const float* __restrict__ bias, // [1024]
    float* __restrict__ Out)        // [8192,1024] fp32
{
    __shared__ f16 lds2[16384];     // 32 KB
    f16* Af[2] = {lds2,        lds2 + 4096};
    f16* Bf[2] = {lds2 + 8192, lds2 + 12288};

    const int t    = threadIdx.x;
    const int lane = t & 63;
    const int w    = t >> 6;
    const int quad = lane >> 4, l15 = lane & 15;
    const int wr = w >> 1, wc = w & 1;
    const int n0 = blockIdx.x * 128;
    const int m0 = blockIdx.y * 128;
    const int wbase = t & 192;

    f32_4 acc[4][4] = {};

    for (int k0 = 0; k0 < 1024; k0 += 64) {
        #pragma unroll
        for (int kc = 0; kc < 2; kc++)
            #pragma unroll
            for (int c = 0; c < 2; c++) {
                int i = c*256 + t;
                const int row = i >> 2, col = (i & 3) * 8;
                gl_lds16(Yb  + (size_t)(m0 + row)*1024 + k0 + kc*32 + col,
                         Af[kc], c*256 + wbase);
                gl_lds16(Wtp + (size_t)(n0 + row)*1024 + k0 + kc*32 + col,
                         Bf[kc], c*256 + wbase);
            }
        __syncthreads();
        #pragma unroll
        for (int kc = 0; kc < 2; kc++) {
            f16_8 af[4], bf[4];
            #pragma unroll
            for (int mi = 0; mi < 4; mi++)
                af[mi] = *(const f16_8*)&Af[kc][(wr*64 + mi*16 + l15)*32 + quad*8];
            #pragma unroll
            for (int ni = 0; ni < 4; ni++)
                bf[ni] = *(const f16_8*)&Bf[kc][(wc*64 + ni*16 + l15)*32 + quad*8];
            #pragma unroll
            for (int mi = 0; mi < 4; mi++)
                #pragma unroll
                for (int ni = 0; ni < 4; ni++)
                    acc[mi][ni] = MFMA32(af[mi], bf[ni], acc[mi][ni]);
        }
        __syncthreads();
    }

    #pragma unroll
    for (int mi = 0; mi < 4; mi++)
    #pragma unroll
    for (int ni = 0; ni < 4; ni++)
    #pragma unroll
    for (int r = 0; r < 4; r++) {
        int m = m0 + wr*64 + mi*16 + quad*4 + r;
        int n = n0 + wc*64 + ni*16 + l15;
        Out[(size_t)m*1024 + n] = acc[mi][ni][r] + bias[n];
    }
}

// ---------------------------------------------------------------------------
extern "C" void kernel_launch(void* const* d_in, const int* in_sizes, int n_in,
                              void* d_out, int out_size, void* d_ws, size_t ws_size,
                              hipStream_t stream) {
    const float* x      = (const float*)d_in[0];
    const float* W_attn = (const float*)d_in[1];
    const float* b_attn = (const float*)d_in[2];
    const float* W_proj = (const float*)d_in[3];
    const float* b_proj = (const float*)d_in[4];
    float* out = (float*)d_out;

    const size_t per = (size_t)B_ * H_ * S_ * HD_;   // 8,388,608 elems
    f16* Yb  = (f16*)d_ws;        // [0, per)      attn output
    f16* Wta = Yb;                //   alias: W_attn^T f16 (dead before Yb written)
    f16* Qb  = Yb + per;          // [per, 2per)
    f16* Kb  = Qb + per;          // [2per, 3per)
    f16* Vt  = Kb + per;          // [3per, 4per)  total 67.1 MB
    f16* Wtp = Qb;                //   alias: W_proj^T f16 (written after attn)
    f16* Xh  = (f16*)d_out;       //   scratch: d_out dead until proj_gemm

    prep     <<<4096 + 768, 256, 0, stream>>>(x, Xh, W_attn, Wta);
    qkv_gemm <<<dim3(24, 64), 256, 0, stream>>>(Xh, Wta, b_attn, Qb, Kb, Vt);
    attn     <<<dim3(64, 8),  256, 0, stream>>>(Qb, Kb, Vt, Yb);
    trans_w  <<<dim3(16, 16), 256, 0, stream>>>(W_proj, Wtp, D_);
    proj_gemm<<<dim3(8, 64),  256, 0, stream>>>(Yb, Wtp, b_proj, out);
}

// Round 11
// 267.102 us; speedup vs baseline: 1.2558x; 1.0137x over previous
//
#include <hip/hip_runtime.h>

#define B_  4
#define S_  2048
#define D_  1024
#define H_  16
#define HD_ 64
#define BS_ (B_*S_)   // 8192

typedef _Float16 f16;
typedef _Float16 f16_8 __attribute__((ext_vector_type(8)));
typedef _Float16 f16_4 __attribute__((ext_vector_type(4)));
typedef float    f32_4 __attribute__((ext_vector_type(4)));
typedef unsigned int u32;

#define MFMA32(a,b,c) __builtin_amdgcn_mfma_f32_16x16x32_f16(a, b, c, 0, 0, 0)
#define MFMA16(a,b,c) __builtin_amdgcn_mfma_f32_16x16x16f16(a, b, c, 0, 0, 0)
#define NEG_INF (-__builtin_inff())

// async global->LDS, 16B per lane. chunk_base in lane units (16B each).
__device__ inline void gl_lds16(const f16* g, f16* lds_base, int chunk_base) {
    __builtin_amdgcn_global_load_lds(
        (const __attribute__((address_space(1))) u32*)g,
        (__attribute__((address_space(3))) u32*)(lds_base + (size_t)chunk_base * 8),
        16, 0, 0);
}

// ---------------------------------------------------------------------------
// prep: blocks [0,4096) convert X fp32->f16; blocks [4096,4864) transpose
// W_attn fp32 [1024][3072] -> Wta f16 [3072][1024].
// ---------------------------------------------------------------------------
__global__ __launch_bounds__(256) void prep(
    const float* __restrict__ X,  f16* __restrict__ Xh,
    const float* __restrict__ Wa, f16* __restrict__ Wta)
{
    __shared__ f16 T[64][72];
    const int t = threadIdx.x;
    const int bid = blockIdx.x;
    if (bid < 4096) {
        const size_t i = ((size_t)bid * 256 + t) * 8;
        float4 a = *(const float4*)&X[i];
        float4 b = *(const float4*)&X[i + 4];
        f16 h[8] = {(f16)a.x,(f16)a.y,(f16)a.z,(f16)a.w,
                    (f16)b.x,(f16)b.y,(f16)b.z,(f16)b.w};
        *(uint4*)&Xh[i] = *(const uint4*)h;
        return;
    }
    const int idx = bid - 4096;
    const int n0 = (idx % 48) * 64, k0 = (idx / 48) * 64;
    const int nl4 = (t & 15) * 4;
    #pragma unroll
    for (int r = 0; r < 4; r++) {
        const int kl = (t >> 4) + r * 16;
        float4 v = *(const float4*)&Wa[(size_t)(k0 + kl) * 3072 + n0 + nl4];
        T[nl4 + 0][kl] = (f16)v.x;
        T[nl4 + 1][kl] = (f16)v.y;
        T[nl4 + 2][kl] = (f16)v.z;
        T[nl4 + 3][kl] = (f16)v.w;
    }
    __syncthreads();
    const int nr = t >> 2, kc = (t & 3) * 16;
    *(uint4*)&Wta[(size_t)(n0 + nr) * 1024 + k0 + kc]     = *(uint4*)&T[nr][kc];
    *(uint4*)&Wta[(size_t)(n0 + nr) * 1024 + k0 + kc + 8] = *(uint4*)&T[nr][kc + 8];
}

// ---------------------------------------------------------------------------
// Transpose + convert: W [1024][ncols] fp32 -> Wt [ncols][1024] f16
// (runs after attn: Wtp aliases the dead Q buffer)
// ---------------------------------------------------------------------------
__global__ __launch_bounds__(256) void trans_w(
    const float* __restrict__ W, f16* __restrict__ Wt, int ncols)
{
    __shared__ f16 T[64][72];
    const int t = threadIdx.x;
    const int n0 = blockIdx.x * 64, k0 = blockIdx.y * 64;
    const int nl4 = (t & 15) * 4;
    #pragma unroll
    for (int r = 0; r < 4; r++) {
        const int kl = (t >> 4) + r * 16;
        float4 v = *(const float4*)&W[(size_t)(k0 + kl) * ncols + n0 + nl4];
        T[nl4 + 0][kl] = (f16)v.x;
        T[nl4 + 1][kl] = (f16)v.y;
        T[nl4 + 2][kl] = (f16)v.z;
        T[nl4 + 3][kl] = (f16)v.w;
    }
    __syncthreads();
    const int nr = t >> 2, kc = (t & 3) * 16;
    *(uint4*)&Wt[(size_t)(n0 + nr) * 1024 + k0 + kc]     = *(uint4*)&T[nr][kc];
    *(uint4*)&Wt[(size_t)(n0 + nr) * 1024 + k0 + kc + 8] = *(uint4*)&T[nr][kc + 8];
}

// ---------------------------------------------------------------------------
// GEMM1: qkv = x @ W_attn + b_attn.  f16 operands, full async staging,
// 128x128 tile, BK=64 as 2x[128][32] chunks.
// Grid (m=64, n=24): XCD_id = m%8 -> each XCD's 8 X-strips (2 MB) stay in
// its L2; W streamed once per XCD.
// ---------------------------------------------------------------------------
__global__ __launch_bounds__(256) void qkv_gemm(
    const f16*   __restrict__ Xh,    // [8192,1024] f16
    const f16*   __restrict__ Wta,   // [3072,1024] f16 (pre-transposed)
    const float* __restrict__ bias,  // [3072]
    f16* __restrict__ Qb, f16* __restrict__ Kb, f16* __restrict__ Vt)
{
    __shared__ f16 lds[17408];          // 34.8 KB (epilogue Ct reuse)
    f16* Af[2] = {lds,        lds + 4096};
    f16* Bf[2] = {lds + 8192, lds + 12288};
    f16* Ct    = lds;                   // [128][136]

    const int t    = threadIdx.x;
    const int lane = t & 63;
    const int w    = t >> 6;
    const int quad = lane >> 4, l15 = lane & 15;
    const int wr = w >> 1, wc = w & 1;
    const int m0 = blockIdx.x * 128;    // m fastest -> X strips XCD-local
    const int n0 = blockIdx.y * 128;
    const int wbase = t & 192;          // wave-uniform

    f32_4 acc[4][4] = {};

    for (int k0 = 0; k0 < 1024; k0 += 64) {
        #pragma unroll
        for (int kc = 0; kc < 2; kc++)
            #pragma unroll
            for (int c = 0; c < 2; c++) {
                int i = c*256 + t;
                const int row = i >> 2, col = (i & 3) * 8;
                gl_lds16(Xh  + (size_t)(m0 + row)*1024 + k0 + kc*32 + col,
                         Af[kc], c*256 + wbase);
                gl_lds16(Wta + (size_t)(n0 + row)*1024 + k0 + kc*32 + col,
                         Bf[kc], c*256 + wbase);
            }
        __syncthreads();

        #pragma unroll
        for (int kc = 0; kc < 2; kc++) {
            f16_8 af[4], bf[4];
            #pragma unroll
            for (int mi = 0; mi < 4; mi++)
                af[mi] = *(const f16_8*)&Af[kc][(wr*64 + mi*16 + l15)*32 + quad*8];
            #pragma unroll
            for (int ni = 0; ni < 4; ni++)
                bf[ni] = *(const f16_8*)&Bf[kc][(wc*64 + ni*16 + l15)*32 + quad*8];
            #pragma unroll
            for (int mi = 0; mi < 4; mi++)
                #pragma unroll
                for (int ni = 0; ni < 4; ni++)
                    acc[mi][ni] = MFMA32(af[mi], bf[ni], acc[mi][ni]);
        }
        __syncthreads();
    }

    const int which = n0 >> 10;      // 0=Q 1=K 2=V (block-uniform)
    float bcol[4];
    #pragma unroll
    for (int ni = 0; ni < 4; ni++)
        bcol[ni] = bias[n0 + wc*64 + ni*16 + l15];

    if (which < 2) {
        f16* dst = (which == 0) ? Qb : Kb;
        const float sc = (which == 0) ? 0.125f * 1.44269504f : 1.0f;
        #pragma unroll
        for (int mi = 0; mi < 4; mi++)
        #pragma unroll
        for (int ni = 0; ni < 4; ni++)
        #pragma unroll
        for (int r = 0; r < 4; r++) {
            int m = m0 + wr*64 + mi*16 + quad*4 + r;
            int n = (n0 & 1023) + wc*64 + ni*16 + l15;
            int h = n >> 6, hd = n & 63;
            int b = m >> 11, s = m & 2047;
            dst[((size_t)(b*16 + h)*2048 + s)*64 + hd] =
                (f16)((acc[mi][ni][r] + bcol[ni]) * sc);
        }
    } else {
        #pragma unroll
        for (int mi = 0; mi < 4; mi++)
        #pragma unroll
        for (int ni = 0; ni < 4; ni++)
        #pragma unroll
        for (int r = 0; r < 4; r++) {
            int nl = wc*64 + ni*16 + l15;
            int ml = wr*64 + mi*16 + quad*4 + r;
            Ct[nl*136 + ml] = (f16)(acc[mi][ni][r] + bcol[ni]);
        }
        __syncthreads();
        const int row = t >> 1, sc4 = (t & 1) * 64;
        const int n = (n0 & 1023) + row;
        const int h = n >> 6, hd = n & 63;
        const int b = m0 >> 11, s0 = (m0 & 2047) + sc4;
        f16* dst = Vt + ((size_t)(b*16 + h)*64 + hd)*2048 + s0;
        #pragma unroll
        for (int j = 0; j < 8; j++)
            *(uint4*)&dst[j*8] = *(uint4*)&Ct[row*136 + sc4 + j*8];
    }
}

// ---------------------------------------------------------------------------
// Flash causal attention (round-5 structure): 4-wave blocks, 128-row strips,
// pair {qb, 15-qb} as two sequential passes (34 tiles/block, uniform).
// Grid (bh=64, pair=8): all 8 pair-blocks of one bh share linear id%8 ->
// same XCD -> L2 caches that bh's K/V.  [validated r10: attn left top-5]
// Fixed-max exp2 softmax, P^T in registers, l via pre-summed P MFMA.
// ---------------------------------------------------------------------------
__global__ __launch_bounds__(256) void attn(
    const f16* __restrict__ Qb,
    const f16* __restrict__ Kb,
    const f16* __restrict__ Vt,     // [bh][hd][s]
    f16* __restrict__ Y)            // [8192,1024]
{
    __shared__ f16 Ks[64*72];       // [key][hd]
    __shared__ f16 Vs[64*72];       // [hd][key]

    const int t    = threadIdx.x;
    const int w    = t >> 6;
    const int lane = t & 63;
    const int quad = lane >> 4, l15 = lane & 15;
    const int bh   = blockIdx.x;    // swizzle: bh fastest -> same XCD
    const int b    = bh >> 4, h = bh & 15;

    const f16* qh = Qb + (size_t)bh * S_ * 64;
    const f16* kh = Kb + (size_t)bh * S_ * 64;
    const f16* vt = Vt + (size_t)bh * 64 * S_;

    const int sk = t >> 2, sc = (t & 3) * 8;
    const f16_4 ones = {(f16)1,(f16)1,(f16)1,(f16)1};

    #pragma unroll 1
    for (int sp = 0; sp < 2; sp++) {
        const int qb = sp ? 15 - (int)blockIdx.y : (int)blockIdx.y;
        const int qw = qb*128 + w*32;

        f16_8 qa[2][2];
        #pragma unroll
        for (int rt = 0; rt < 2; rt++)
            #pragma unroll
            for (int c = 0; c < 2; c++)
                qa[rt][c] = *(const f16_8*)&qh[(size_t)(qw + rt*16 + l15)*64 + c*32 + quad*8];

        f32_4 o[2][4] = {};
        f32_4 lacc[2] = {};
        const int ntiles = 2*qb + 2;

        for (int kt = 0; kt < ntiles; kt++) {
            const int kbase = kt * 64;
            *(uint4*)&Ks[sk*72 + sc]      = *(const uint4*)&kh[(size_t)(kbase + sk)*64 + sc];
            *(uint4*)&Ks[sk*72 + sc + 32] = *(const uint4*)&kh[(size_t)(kbase + sk)*64 + sc + 32];
            *(uint4*)&Vs[sk*72 + sc]      = *(const uint4*)&vt[(size_t)sk*2048 + kbase + sc];
            *(uint4*)&Vs[sk*72 + sc + 32] = *(const uint4*)&vt[(size_t)sk*2048 + kbase + sc + 32];
            __syncthreads();

            if (kbase <= qw + 31) {      // wave-uniform
                // ---- S^T = K Q^T : rows=key(quad*4+r), cols=qrow(l15) ----
                f16_8 kb[4][2];
                #pragma unroll
                for (int sub = 0; sub < 4; sub++)
                    #pragma unroll
                    for (int c = 0; c < 2; c++)
                        kb[sub][c] = *(const f16_8*)&Ks[(sub*16 + l15)*72 + c*32 + quad*8];
                f32_4 st[2][4];
                #pragma unroll
                for (int rt = 0; rt < 2; rt++)
                    #pragma unroll
                    for (int sub = 0; sub < 4; sub++) {
                        f32_4 a = {};
                        a = MFMA32(kb[sub][0], qa[rt][0], a);
                        a = MFMA32(kb[sub][1], qa[rt][1], a);
                        st[rt][sub] = a;
                    }

                // ---- P^T = exp2(S^T), packed as 16x16x16 A-fragments ----
                const bool masked = (kbase + 63 > qw);
                f16_4 pt[2][4];
                #pragma unroll
                for (int rt = 0; rt < 2; rt++)
                #pragma unroll
                for (int sub = 0; sub < 4; sub++) {
                    const int qrow = qw + rt*16 + l15;
                    f16_4 p;
                    #pragma unroll
                    for (int r = 0; r < 4; r++) {
                        float x = st[rt][sub][r];
                        if (masked) {
                            int key = kbase + sub*16 + quad*4 + r;
                            x = (key <= qrow) ? x : NEG_INF;
                        }
                        p[r] = (f16)__builtin_amdgcn_exp2f(x);
                    }
                    pt[rt][sub] = p;
                }

                // ---- l += (sum_sub P) . 1  (one MFMA per rt) ----
                #pragma unroll
                for (int rt = 0; rt < 2; rt++) {
                    f16_4 ps = (pt[rt][0] + pt[rt][1]) + (pt[rt][2] + pt[rt][3]);
                    lacc[rt] = MFMA16(ps, ones, lacc[rt]);
                }

                // ---- O += P V ----
                #pragma unroll
                for (int sub = 0; sub < 4; sub++) {
                    f16_4 vb[4];
                    #pragma unroll
                    for (int tt = 0; tt < 4; tt++)
                        vb[tt] = *(const f16_4*)&Vs[(tt*16 + l15)*72 + sub*16 + quad*4];
                    #pragma unroll
                    for (int rt = 0; rt < 2; rt++)
                        #pragma unroll
                        for (int tt = 0; tt < 4; tt++)
                            o[rt][tt] = MFMA16(pt[rt][sub], vb[tt], o[rt][tt]);
                }
            }
            __syncthreads();
        }

        // epilogue: normalize, write Y
        #pragma unroll
        for (int rt = 0; rt < 2; rt++)
        #pragma unroll
        for (int r = 0; r < 4; r++) {
            float inv = 1.0f / lacc[rt][r];
            int srow = qw + rt*16 + quad*4 + r;
            #pragma unroll
            for (int tt = 0; tt < 4; tt++)
                Y[(size_t)(b*S_ + srow)*1024 + h*64 + tt*16 + l15] =
                    (f16)(o[rt][tt][r] * inv);
        }
    }
}

// ---------------------------------------------------------------------------
// GEMM2: out = y @ W_proj + b_proj.  Full async, BK=64 double-chunk.
// Grid (m=64, n=8): XCD_id = m%8 -> Y strips XCD-local.
// ---------------------------------------------------------------------------
__global__ __launch_bounds__(256) void proj_gemm(
    const f16* __restrict__ Yb,     // [8192,1024]
    const f16* __restrict__ Wtp,    // [1024,1024] (pre-transposed)
    const float* __restrict__ bias, // [1024]
    float* __restrict__ Out)        // [8192,1024] fp32
{
    __shared__ f16 lds2[16384];     // 32 KB
    f16* Af[2] = {lds2,        lds2 + 4096};
    f16* Bf[2] = {lds2 + 8192, lds2 + 12288};

    const int t    = threadIdx.x;
    const int lane = t & 63;
    const int w    = t >> 6;
    const int quad = lane >> 4, l15 = lane & 15;
    const int wr = w >> 1, wc = w & 1;
    const int m0 = blockIdx.x * 128;    // m fastest -> Y strips XCD-local
    const int n0 = blockIdx.y * 128;
    const int wbase = t & 192;

    f32_4 acc[4][4] = {};

    for (int k0 = 0; k0 < 1024; k0 += 64) {
        #pragma unroll
        for (int kc = 0; kc < 2; kc++)
            #pragma unroll
            for (int c = 0; c < 2; c++) {
                int i = c*256 + t;
                const int row = i >> 2, col = (i & 3) * 8;
                gl_lds16(Yb  + (size_t)(m0 + row)*1024 + k0 + kc*32 + col,
                         Af[kc], c*256 + wbase);
                gl_lds16(Wtp + (size_t)(n0 + row)*1024 + k0 + kc*32 + col,
                         Bf[kc], c*256 + wbase);
            }
        __syncthreads();
        #pragma unroll
        for (int kc = 0; kc < 2; kc++) {
            f16_8 af[4], bf[4];
            #pragma unroll
            for (int mi = 0; mi < 4; mi++)
                af[mi] = *(const f16_8*)&Af[kc][(wr*64 + mi*16 + l15)*32 + quad*8];
            #pragma unroll
            for (int ni = 0; ni < 4; ni++)
                bf[ni] = *(const f16_8*)&Bf[kc][(wc*64 + ni*16 + l15)*32 + quad*8];
            #pragma unroll
            for (int mi = 0; mi < 4; mi++)
                #pragma unroll
                for (int ni = 0; ni < 4; ni++)
                    acc[mi][ni] = MFMA32(af[mi], bf[ni], acc[mi][ni]);
        }
        __syncthreads();
    }

    #pragma unroll
    for (int mi = 0; mi < 4; mi++)
    #pragma unroll
    for (int ni = 0; ni < 4; ni++)
    #pragma unroll
    for (int r = 0; r < 4; r++) {
        int m = m0 + wr*64 + mi*16 + quad*4 + r;
        int n = n0 + wc*64 + ni*16 + l15;
        Out[(size_t)m*1024 + n] = acc[mi][ni][r] + bias[n];
    }
}

// ---------------------------------------------------------------------------
extern "C" void kernel_launch(void* const* d_in, const int* in_sizes, int n_in,
                              void* d_out, int out_size, void* d_ws, size_t ws_size,
                              hipStream_t stream) {
    const float* x      = (const float*)d_in[0];
    const float* W_attn = (const float*)d_in[1];
    const float* b_attn = (const float*)d_in[2];
    const float* W_proj = (const float*)d_in[3];
    const float* b_proj = (const float*)d_in[4];
    float* out = (float*)d_out;

    const size_t per = (size_t)B_ * H_ * S_ * HD_;   // 8,388,608 elems
    f16* Yb  = (f16*)d_ws;        // [0, per)      attn output
    f16* Wta = Yb;                //   alias: W_attn^T f16 (dead before Yb written)
    f16* Qb  = Yb + per;          // [per, 2per)
    f16* Kb  = Qb + per;          // [2per, 3per)
    f16* Vt  = Kb + per;          // [3per, 4per)  total 67.1 MB
    f16* Wtp = Qb;                //   alias: W_proj^T f16 (written after attn)
    f16* Xh  = (f16*)d_out;       //   scratch: d_out dead until proj_gemm

    prep     <<<4096 + 768, 256, 0, stream>>>(x, Xh, W_attn, Wta);
    qkv_gemm <<<dim3(64, 24), 256, 0, stream>>>(Xh, Wta, b_attn, Qb, Kb, Vt);
    attn     <<<dim3(64, 8),  256, 0, stream>>>(Qb, Kb, Vt, Yb);
    trans_w  <<<dim3(16, 16), 256, 0, stream>>>(W_proj, Wtp, D_);
    proj_gemm<<<dim3(64, 8),  256, 0, stream>>>(Yb, Wtp, b_proj, out);
}